// Round 3
// baseline (1075.257 us; speedup 1.0000x reference)
//
#include <hip/hip_runtime.h>
#include <hip/hip_bf16.h>

// Shapes fixed by the reference
#define T_TOK 4096
#define I1    512
#define O1    2049
#define O1P   2176        // padded N1 (17*128)
#define K1    4608        // 8*512 spline + 512 silu
#define KLEN1 2304        // split-K=2
#define I2    2049
#define O2    512
#define K2    18560       // 8*2049 spline + 2049 silu + 119 pad, = 290*64
#define SPLITS2 8
#define KLEN2   2368      // 37*64; last split runs 31 iters

typedef __attribute__((ext_vector_type(8))) short short8;
typedef __attribute__((ext_vector_type(4))) float floatx4;
typedef float float4u __attribute__((ext_vector_type(4), aligned(4)));  // 4B-aligned fp32x4
typedef __attribute__((address_space(3))) void* lds_ptr_t;
typedef const __attribute__((address_space(1))) void* gmem_ptr_t;

__device__ __forceinline__ unsigned short f2bf(float f) {
  union { __hip_bfloat16 h; unsigned short u; } cv;
  cv.h = __float2bfloat16(f);
  return cv.u;
}

__device__ __forceinline__ float silu_f(float x) {
  return x / (1.0f + __expf(-x));
}

// W1'[o,k]: k<4096 -> spline_w1[o,k>>3,k&7]*scaler1[o,k>>3]; else base_w1[o,k-4096]; o>=2049 -> 0
__global__ void pack_w1_kernel(const float* __restrict__ bw, const float* __restrict__ sw,
                               const float* __restrict__ sc, unsigned short* __restrict__ W) {
  int k = blockIdx.x * 256 + threadIdx.x;  // grid exact: 18*256 = 4608
  int o = blockIdx.y;                      // < 2176
  float v = 0.0f;
  if (o < O1) {
    if (k < 4096) v = sw[(size_t)o * 4096 + k] * sc[(size_t)o * I1 + (k >> 3)];
    else          v = bw[(size_t)o * I1 + (k - 4096)];
  }
  W[(size_t)o * K1 + k] = f2bf(v);
}

// W2'[o,k]: k<16392 -> spline_w2*scaler2; k<18441 -> base_w2; else 0
__global__ void pack_w2_kernel(const float* __restrict__ bw, const float* __restrict__ sw,
                               const float* __restrict__ sc, unsigned short* __restrict__ W) {
  int k = blockIdx.x * 256 + threadIdx.x;
  if (k >= K2) return;
  int o = blockIdx.y;                      // < 512
  float v = 0.0f;
  if (k < 16392)      v = sw[(size_t)o * 16392 + k] * sc[(size_t)o * I2 + (k >> 3)];
  else if (k < 18441) v = bw[(size_t)o * I2 + (k - 16392)];
  W[(size_t)o * K2 + k] = f2bf(v);
}

// Fused KAN-expand + GEMM:  C = A(S0[,+S1]) @ Bw^T
//   A[m, k] is GENERATED per K-tile into LDS (never materialized in HBM):
//     group gi = k>>3, c = k&7:
//       gi <  I : A = basis_c(h[m, gi])           (cubic B-spline, 4 nonzero of 8)
//       gi >= I : A = silu(h[m, (gi-I)*8 + c])    (0 when index >= I  -> pad)
//     h = S0 (+ S1 when dual=1; fuses layer-1 split-K partial reduce).
//   Bw: (Nrows x Ktot) bf16 row-major, staged via global_load_lds width-16 with
//   XOR chunk swizzle; A written to the same swizzled layout by the generator.
// 128x128 tile, BK=64, 4 waves, mfma_f32_16x16x32_bf16.
// blockIdx.z: split-K slice. useAtomic: atomicAdd into C (pre-zeroed); else
// plain store into C + z*cSplitStride (partial buffers).
__global__ __launch_bounds__(256)
void kan_gemm_kernel(const float* __restrict__ S0, const float* __restrict__ S1, int dual,
                     const unsigned short* __restrict__ Bw, float* __restrict__ C,
                     int I, int Ktot, int N, int ldc, int kLen, int useAtomic, long cSplitStride)
{
  __shared__ __align__(16) unsigned short As[128 * 64];
  __shared__ __align__(16) unsigned short Bs[128 * 64];

  const int tid = threadIdx.x;
  const int bx = blockIdx.x, by = blockIdx.y, bz = blockIdx.z;
  const int ks = bz * kLen;
  int ke = ks + kLen; if (ke > Ktot) ke = Ktot;

  const int w = tid >> 6, L = tid & 63, q = L >> 4, ln = L & 15;
  const int wm = (w & 1) << 6, wn = (w >> 1) << 6;

  // Generator task mapping: thread -> (row = tid&127, groups gh*4 .. gh*4+3)
  const int row = tid & 127;
  const int gh  = tid >> 7;
  const float* s0row = S0 + (long)(by * 128 + row) * I;
  const float* s1row = S1 + (long)(by * 128 + row) * I;

  floatx4 zf = {0.f, 0.f, 0.f, 0.f};
  floatx4 acc[4][4];
#pragma unroll
  for (int mt = 0; mt < 4; ++mt)
#pragma unroll
    for (int nt = 0; nt < 4; ++nt)
      acc[mt][nt] = zf;

  // B staging: 4 chunks/thread, lane-contiguous LDS dest (wave-uniform base + lane*16)
  const unsigned short* gb[4];
  int ldsOff[4];
#pragma unroll
  for (int r = 0; r < 4; ++r) {
    int e = r * 256 + tid;
    int br = e >> 3;
    int cg = (e & 7) ^ (br & 7);
    gb[r] = Bw + ((long)bx * 128 + br) * (long)Ktot + ks + cg * 8;
    ldsOff[r] = e * 8;
  }

  // Software-pipelined A-source prefetch (common spline case: 1 dwordx4/row)
  float4u hv0 = {0,0,0,0}, hv1 = {0,0,0,0};
  int pfGi; bool pfOK;
  {
    int gi0 = (ks >> 3) + gh * 4;
    pfGi = gi0; pfOK = (gi0 + 3 < I);
    if (pfOK) { hv0 = *(const float4u*)(s0row + gi0); if (dual) hv1 = *(const float4u*)(s1row + gi0); }
  }

  for (int kc = ks; kc < ke; kc += 64) {
    __syncthreads();                       // protect LDS from prior iter's readers
#pragma unroll
    for (int r = 0; r < 4; ++r) {          // B DMA first: in flight during A-generation
      __builtin_amdgcn_global_load_lds((gmem_ptr_t)gb[r], (lds_ptr_t)&Bs[ldsOff[r]], 16, 0, 0);
      gb[r] += 64;
    }

    const int curGi = pfGi; const bool curOK = pfOK;
    const float4u ch0 = hv0, ch1 = hv1;
    if (kc + 64 < ke) {                    // issue next iter's source loads now
      int gi0 = ((kc + 64) >> 3) + gh * 4;
      pfGi = gi0; pfOK = (gi0 + 3 < I);
      if (pfOK) { hv0 = *(const float4u*)(s0row + gi0); if (dual) hv1 = *(const float4u*)(s1row + gi0); }
    }

    // Generate A tile (4 groups/thread) into swizzled LDS layout
#pragma unroll
    for (int j2 = 0; j2 < 4; ++j2) {
      int g  = gh * 4 + j2;
      int gi = curGi + j2;
      int pos = row * 64 + ((g ^ (row & 7)) << 3);
      if (gi < I) {
        float h;
        if (curOK) { h = ch0[j2]; if (dual) h += ch1[j2]; }
        else       { h = s0row[gi]; if (dual) h += s1row[gi]; }
        uint4 z4 = make_uint4(0u, 0u, 0u, 0u);
        *(uint4*)&As[pos] = z4;            // zero the 8-slot group (own chunk, no race)
        if (h >= -2.2f && h < 2.2f) {
          float u = (h + 2.2f) * 2.5f;
          int ji = (int)u; if (ji > 10) ji = 10;
          float t = u - (float)ji;
          float it = 1.0f - t, t2 = t * t, t3 = t2 * t;
          float b0 = it * it * it * (1.0f / 6.0f);
          float b1 = (3.0f * t3 - 6.0f * t2 + 4.0f) * (1.0f / 6.0f);
          float b2 = (-3.0f * t3 + 3.0f * t2 + 3.0f * t + 1.0f) * (1.0f / 6.0f);
          float b3 = t3 * (1.0f / 6.0f);
          int c0 = ji - 3;                 // scatter 4 nonzero bases into own 16B chunk
          int c;
          c = c0 + 0; if (c >= 0 && c < 8) As[pos + c] = f2bf(b0);
          c = c0 + 1; if (c >= 0 && c < 8) As[pos + c] = f2bf(b1);
          c = c0 + 2; if (c >= 0 && c < 8) As[pos + c] = f2bf(b2);
          c = c0 + 3; if (c >= 0 && c < 8) As[pos + c] = f2bf(b3);
        }
      } else {                             // silu region (+ implicit zero pad)
        int off0 = (gi - I) << 3;
        union { unsigned short s[8]; uint4 v; } pk;
#pragma unroll
        for (int c = 0; c < 8; ++c) {
          int off = off0 + c;
          float v = 0.0f;
          if (off < I) { v = s0row[off]; if (dual) v += s1row[off]; v = silu_f(v); }
          pk.s[c] = f2bf(v);
        }
        *(uint4*)&As[pos] = pk.v;
      }
    }
    __syncthreads();                       // A generated + B DMA drained

#pragma unroll
    for (int s = 0; s < 2; ++s) {
      short8 af[4], bf[4];
#pragma unroll
      for (int mt = 0; mt < 4; ++mt) {
        int rr = wm + mt * 16 + ln;
        int cl = ((s << 2) | q) ^ (rr & 7);
        af[mt] = *(const short8*)&As[rr * 64 + cl * 8];
      }
#pragma unroll
      for (int nt = 0; nt < 4; ++nt) {
        int rr = wn + nt * 16 + ln;
        int cl = ((s << 2) | q) ^ (rr & 7);
        bf[nt] = *(const short8*)&Bs[rr * 64 + cl * 8];
      }
#pragma unroll
      for (int mt = 0; mt < 4; ++mt)
#pragma unroll
        for (int nt = 0; nt < 4; ++nt)
          acc[mt][nt] = __builtin_amdgcn_mfma_f32_16x16x32_bf16(af[mt], bf[nt], acc[mt][nt], 0, 0, 0);
    }
  }

  // Epilogue: D col = lane&15 (n), row = q*4+reg (m)  [m89-verified layout]
  float* Cz = C + (long)bz * cSplitStride;
#pragma unroll
  for (int mt = 0; mt < 4; ++mt) {
#pragma unroll
    for (int nt = 0; nt < 4; ++nt) {
      int n = bx * 128 + wn + nt * 16 + ln;
      if (n < N) {
        int m0 = by * 128 + wm + mt * 16 + q * 4;
#pragma unroll
        for (int rg = 0; rg < 4; ++rg) {
          long off = (long)(m0 + rg) * ldc + n;
          float v = acc[mt][nt][rg];
          if (useAtomic) atomicAdd(&Cz[off], v);
          else           Cz[off] = v;
        }
      }
    }
  }
}

extern "C" void kernel_launch(void* const* d_in, const int* in_sizes, int n_in,
                              void* d_out, int out_size, void* d_ws, size_t ws_size,
                              hipStream_t stream) {
  const float* x   = (const float*)d_in[0];
  const float* bw1 = (const float*)d_in[1];
  const float* sw1 = (const float*)d_in[2];
  const float* sc1 = (const float*)d_in[3];
  const float* bw2 = (const float*)d_in[4];
  const float* sw2 = (const float*)d_in[5];
  const float* sc2 = (const float*)d_in[6];
  float* out = (float*)d_out;

  // Workspace: H0 | H1 (fp32 split-K partials of layer 1) | W1' | W2'  (~106 MB)
  float* H0 = (float*)d_ws;
  float* H1 = H0 + (size_t)T_TOK * O1;
  unsigned short* W1 = (unsigned short*)(H1 + (size_t)T_TOK * O1);
  unsigned short* W2 = W1 + (size_t)O1P * K1;

  hipMemsetAsync(d_out, 0, (size_t)out_size * sizeof(float), stream);

  pack_w1_kernel<<<dim3(K1 / 256, O1P), 256, 0, stream>>>(bw1, sw1, sc1, W1);
  pack_w2_kernel<<<dim3((K2 + 255) / 256, O2), 256, 0, stream>>>(bw2, sw2, sc2, W2);

  // Layer 1: H0/H1 = expand(x) @ W1'^T   M=4096, N=2049(pad 2176), K=4608, split-K=2
  // (A generated from x in-kernel; partials plain-stored, reduced by layer 2's dual read)
  kan_gemm_kernel<<<dim3(O1P / 128, T_TOK / 128, 2), 256, 0, stream>>>(
      x, x, 0, W1, H0, I1, K1, O1, O1, KLEN1, 0, (long)T_TOK * O1);

  // Layer 2: out += expand(H0+H1) @ W2'^T  M=4096, N=512, K=18560, split-K=8, atomics
  kan_gemm_kernel<<<dim3(O2 / 128, T_TOK / 128, SPLITS2), 256, 0, stream>>>(
      H0, H1, 1, W2, out, I2, K2, O2, O2, KLEN2, 1, 0);
}

// Round 4
// 799.766 us; speedup vs baseline: 1.3445x; 1.3445x over previous
//
#include <hip/hip_runtime.h>
#include <hip/hip_bf16.h>

// Shapes fixed by the reference
#define T_TOK 4096
#define I1    512
#define O1    2049
#define O1P   2176        // padded N1 (17*128)
#define K1    4608        // 8*512 spline + 512 silu
#define SPLITS1 2
#define KLEN1 2304
#define I2    2049
#define O2    512
#define K2    18560       // 8*2049 spline + 2049 silu + 119 pad = 290*64
#define SPLITS2 8
#define KLEN2 2368        // 37*64; last slice clamps to 31 iters

typedef __attribute__((ext_vector_type(8))) short short8;
typedef __attribute__((ext_vector_type(4))) float floatx4;
typedef __attribute__((address_space(3))) void* lds_ptr_t;
typedef const __attribute__((address_space(1))) void* gmem_ptr_t;

__device__ __forceinline__ unsigned short f2bf(float f) {
  union { __hip_bfloat16 h; unsigned short u; } cv;
  cv.h = __float2bfloat16(f);
  return cv.u;
}

__device__ __forceinline__ float silu_f(float x) {
  return x / (1.0f + __expf(-x));
}

// All 8 cubic-basis slots for one group, packed as 8 bf16 in a uint4.
// Nonzero bases b0..b3 sit at slots c0..c0+3 (c0 = interval-3); placement via a
// branchless 128-bit funnel shift. Clipping at slots 0/7 == reference truncation.
__device__ __forceinline__ uint4 spline_pack(float h) {
  float u = (h + 2.2f) * 2.5f;
  int ji = (int)u;
  ji = ji < 0 ? 0 : (ji > 10 ? 10 : ji);
  float t = u - (float)ji;
  float it = 1.0f - t, t2 = t * t, t3 = t2 * t;
  float b0 = it * it * it * (1.0f / 6.0f);
  float b1 = (3.0f * t3 - 6.0f * t2 + 4.0f) * (1.0f / 6.0f);
  float b2 = (-3.0f * t3 + 3.0f * t2 + 3.0f * t + 1.0f) * (1.0f / 6.0f);
  float b3 = t3 * (1.0f / 6.0f);
  unsigned pk01 = (unsigned)f2bf(b0) | ((unsigned)f2bf(b1) << 16);
  unsigned pk23 = (unsigned)f2bf(b2) | ((unsigned)f2bf(b3) << 16);
  unsigned long long p64 = (unsigned long long)pk01 | ((unsigned long long)pk23 << 32);
  bool inR = (h >= -2.2f) && (h < 2.2f);
  p64 = inR ? p64 : 0ull;
  int sh = (ji - 3) * 16;
  int shr = sh < 0 ? -sh : 0;
  int shl = sh < 0 ? 0 : sh;
  __uint128_t v = ((__uint128_t)(p64 >> shr)) << shl;
  union { __uint128_t q; uint4 u4; } cv;
  cv.q = v;
  return cv.u4;
}

// 32x32 LDS-tiled transpose: src (R x C) -> dst (C x R). R,C multiples of 32.
__global__ void transpose_kernel(const float* __restrict__ src, float* __restrict__ dst,
                                 int R, int C) {
  __shared__ float t[32][33];
  int c0 = blockIdx.x * 32, r0 = blockIdx.y * 32;
  int tx = threadIdx.x & 31, ty = threadIdx.x >> 5;   // 32 x 8
#pragma unroll
  for (int i = 0; i < 32; i += 8)
    t[ty + i][tx] = src[(size_t)(r0 + ty + i) * C + c0 + tx];
  __syncthreads();
#pragma unroll
  for (int i = 0; i < 32; i += 8)
    dst[(size_t)(c0 + ty + i) * R + r0 + tx] = t[tx][ty + i];
}

// W1'[o,k]: k<4096 -> spline_w1[o,k>>3,k&7]*scaler1[o,k>>3]; else base_w1; o>=2049 -> 0
__global__ void pack_w1_kernel(const float* __restrict__ bw, const float* __restrict__ sw,
                               const float* __restrict__ sc, unsigned short* __restrict__ W) {
  int k = blockIdx.x * 256 + threadIdx.x;  // grid exact: 18*256 = 4608
  int o = blockIdx.y;                      // < 2176
  float v = 0.0f;
  if (o < O1) {
    if (k < 4096) v = sw[(size_t)o * 4096 + k] * sc[(size_t)o * I1 + (k >> 3)];
    else          v = bw[(size_t)o * I1 + (k - 4096)];
  }
  W[(size_t)o * K1 + k] = f2bf(v);
}

// W2'[o,k]: k<16392 -> spline_w2*scaler2; k<18441 -> base_w2; else 0
__global__ void pack_w2_kernel(const float* __restrict__ bw, const float* __restrict__ sw,
                               const float* __restrict__ sc, unsigned short* __restrict__ W) {
  int k = blockIdx.x * 256 + threadIdx.x;
  if (k >= K2) return;
  int o = blockIdx.y;                      // < 512
  float v = 0.0f;
  if (k < 16392)      v = sw[(size_t)o * 16392 + k] * sc[(size_t)o * I2 + (k >> 3)];
  else if (k < 18441) v = bw[(size_t)o * I2 + (k - 16392)];
  W[(size_t)o * K2 + k] = f2bf(v);
}

// Fused KAN-expand + GEMM with TRANSPOSED sources.
//   S0t,S1t: (I x M) fp32, row = input feature, col = token (h = S0t[+S1t if dual]).
//   A[m,k] generated per K-tile into swizzled LDS: group gi=k>>3, c=k&7:
//     gi <  I : basis_c(h[gi, m])    (one ds_write_b128 per group, branchless pack)
//     gi >= I : silu(h[(gi-I)*8+c, m]) or 0 pad
//   All source reads: lane = m -> consecutive addresses (coalesced dwords).
//   Bw (Nrows x Ktot bf16) staged via global_load_lds width-16, XOR chunk swizzle.
// 128x128 tile, BK=64, 4 waves, mfma_f32_16x16x32_bf16.
// storeMode 1: C^T float4 store at Cz[n*ldc + m] (layer-1 partials, ldc = M).
// storeMode 2: atomicAdd C[m*ldc + n] (layer-2, C pre-zeroed, split-K).
__global__ __launch_bounds__(256, 4)
void kan_gemm_kernel(const float* __restrict__ S0t, const float* __restrict__ S1t, int dual,
                     const unsigned short* __restrict__ Bw, float* __restrict__ C,
                     int I, int Ktot, int M, int N, int ldc, int kLen,
                     int storeMode, long cSplitStride)
{
  __shared__ __align__(16) unsigned short As[128 * 64];
  __shared__ __align__(16) unsigned short Bs[128 * 64];

  const int tid = threadIdx.x;
  const int bx = blockIdx.x, by = blockIdx.y, bz = blockIdx.z;
  const int ks = bz * kLen;
  int ke = ks + kLen; if (ke > Ktot) ke = Ktot;

  const int w = tid >> 6, L = tid & 63, q = L >> 4, ln = L & 15;
  const int wm = (w & 1) << 6, wn = (w >> 1) << 6;

  // Generator mapping: thread -> (m-row = tid&127, 4 groups starting at gh*4)
  const int row = tid & 127;
  const int gh  = tid >> 7;
  const int mGlob = by * 128 + row;
  const float* s0 = S0t + mGlob;           // column of S0t; + gi*M indexes feature gi
  const float* s1 = S1t + mGlob;

  floatx4 zf = {0.f, 0.f, 0.f, 0.f};
  floatx4 acc[4][4];
#pragma unroll
  for (int mt = 0; mt < 4; ++mt)
#pragma unroll
    for (int nt = 0; nt < 4; ++nt)
      acc[mt][nt] = zf;

  // B staging: 4 chunks/thread, lane-contiguous LDS dest (wave-uniform base + lane*16)
  const unsigned short* gb[4];
  int ldsOff[4];
#pragma unroll
  for (int r = 0; r < 4; ++r) {
    int e = r * 256 + tid;
    int br = e >> 3;
    int cg = (e & 7) ^ (br & 7);
    gb[r] = Bw + ((long)bx * 128 + br) * (long)Ktot + ks + cg * 8;
    ldsOff[r] = e * 8;
  }

  for (int kc = ks; kc < ke; kc += 64) {
    __syncthreads();                        // protect LDS from prior iter's readers
#pragma unroll
    for (int r = 0; r < 4; ++r) {           // B DMA first: in flight during A-generation
      __builtin_amdgcn_global_load_lds((gmem_ptr_t)gb[r], (lds_ptr_t)&Bs[ldsOff[r]], 16, 0, 0);
      gb[r] += 64;
    }

    const int gBase = (kc >> 3) + gh * 4;
#pragma unroll
    for (int j2 = 0; j2 < 4; ++j2) {
      int g  = gh * 4 + j2;                 // local group 0..7 (wave-uniform)
      int gi = gBase + j2;
      int pos = row * 64 + ((g ^ (row & 7)) << 3);
      uint4 val;
      if (gi < I) {                         // spline group (wave-uniform branch)
        float h = s0[(size_t)gi * M];       // coalesced: lane = m
        if (dual) h += s1[(size_t)gi * M];
        val = spline_pack(h);
      } else {                              // silu group (+ implicit zero pad)
        int off0 = (gi - I) << 3;
        union { unsigned short s[8]; uint4 v; } pk;
#pragma unroll
        for (int c = 0; c < 8; ++c) {
          int off = off0 + c;
          float v = 0.0f;
          if (off < I) {                    // wave-uniform condition
            v = s0[(size_t)off * M];
            if (dual) v += s1[(size_t)off * M];
            v = silu_f(v);
          }
          pk.s[c] = f2bf(v);
        }
        val = pk.v;
      }
      *(uint4*)&As[pos] = val;              // one ds_write_b128, swizzle-spread
    }
    __syncthreads();                        // A generated + B DMA drained

#pragma unroll
    for (int s = 0; s < 2; ++s) {
      short8 af[4], bf[4];
#pragma unroll
      for (int mt = 0; mt < 4; ++mt) {
        int rr = wm + mt * 16 + ln;
        int cl = ((s << 2) | q) ^ (rr & 7);
        af[mt] = *(const short8*)&As[rr * 64 + cl * 8];
      }
#pragma unroll
      for (int nt = 0; nt < 4; ++nt) {
        int rr = wn + nt * 16 + ln;
        int cl = ((s << 2) | q) ^ (rr & 7);
        bf[nt] = *(const short8*)&Bs[rr * 64 + cl * 8];
      }
#pragma unroll
      for (int mt = 0; mt < 4; ++mt)
#pragma unroll
        for (int nt = 0; nt < 4; ++nt)
          acc[mt][nt] = __builtin_amdgcn_mfma_f32_16x16x32_bf16(af[mt], bf[nt], acc[mt][nt], 0, 0, 0);
    }
  }

  // Epilogue. D layout: col = lane&15 (n), row = q*4+reg (m)  [m89-verified]
  if (storeMode == 1) {                     // transposed float4 partial store (layer 1)
    float* Cz = C + (long)bz * cSplitStride;
#pragma unroll
    for (int mt = 0; mt < 4; ++mt) {
#pragma unroll
      for (int nt = 0; nt < 4; ++nt) {
        int n = bx * 128 + wn + nt * 16 + ln;
        if (n < N) {
          int m0 = by * 128 + wm + mt * 16 + q * 4;
          *(float4*)&Cz[(size_t)n * ldc + m0] = *(float4*)&acc[mt][nt];
        }
      }
    }
  } else {                                  // atomic accumulate (layer 2)
#pragma unroll
    for (int mt = 0; mt < 4; ++mt) {
#pragma unroll
      for (int nt = 0; nt < 4; ++nt) {
        int n = bx * 128 + wn + nt * 16 + ln;
        if (n < N) {
          int m0 = by * 128 + wm + mt * 16 + q * 4;
#pragma unroll
          for (int rg = 0; rg < 4; ++rg)
            atomicAdd(&C[(size_t)(m0 + rg) * ldc + n], acc[mt][nt][rg]);
        }
      }
    }
  }
}

extern "C" void kernel_launch(void* const* d_in, const int* in_sizes, int n_in,
                              void* d_out, int out_size, void* d_ws, size_t ws_size,
                              hipStream_t stream) {
  const float* x   = (const float*)d_in[0];
  const float* bw1 = (const float*)d_in[1];
  const float* sw1 = (const float*)d_in[2];
  const float* sc1 = (const float*)d_in[3];
  const float* bw2 = (const float*)d_in[4];
  const float* sw2 = (const float*)d_in[5];
  const float* sc2 = (const float*)d_in[6];
  float* out = (float*)d_out;

  // Workspace: Xt | H0t | H1t | W1' | W2'   (~114.6 MB)
  float* Xt  = (float*)d_ws;                                  // 512 x 4096   =  8.39 MB
  float* H0t = Xt  + (size_t)I1 * T_TOK;                      // 2049 x 4096  = 33.57 MB
  float* H1t = H0t + (size_t)O1 * T_TOK;                      // 2049 x 4096  = 33.57 MB
  unsigned short* W1 = (unsigned short*)(H1t + (size_t)O1 * T_TOK);  // 20.05 MB
  unsigned short* W2 = W1 + (size_t)O1P * K1;                        // 19.01 MB

  hipMemsetAsync(d_out, 0, (size_t)out_size * sizeof(float), stream);

  transpose_kernel<<<dim3(I1 / 32, T_TOK / 32), 256, 0, stream>>>(x, Xt, T_TOK, I1);
  pack_w1_kernel<<<dim3(K1 / 256, O1P), 256, 0, stream>>>(bw1, sw1, sc1, W1);
  pack_w2_kernel<<<dim3((K2 + 255) / 256, O2), 256, 0, stream>>>(bw2, sw2, sc2, W2);

  // Layer 1: H^T partials = expand(x) @ W1'^T, stored transposed.
  // M=4096, N=2049(pad 2176), K=4608, split-K=2 -> 1088 blocks.
  kan_gemm_kernel<<<dim3(O1P / 128, T_TOK / 128, SPLITS1), 256, 0, stream>>>(
      Xt, Xt, 0, W1, H0t, I1, K1, T_TOK, O1, T_TOK, KLEN1, 1, (long)O1 * T_TOK);

  // Layer 2: out += expand(H0t+H1t) @ W2'^T. M=4096, N=512, K=18560, split-K=8 -> 1024 blocks.
  kan_gemm_kernel<<<dim3(O2 / 128, T_TOK / 128, SPLITS2), 256, 0, stream>>>(
      H0t, H1t, 1, W2, out, I2, K2, T_TOK, O2, O2, KLEN2, 2, 0);
}

// Round 5
// 505.499 us; speedup vs baseline: 2.1271x; 1.5821x over previous
//
#include <hip/hip_runtime.h>
#include <hip/hip_bf16.h>

// Shapes fixed by the reference
#define T_TOK 4096
#define I1    512
#define O1    2049
#define O1P   2176        // padded N1 rows (17*128)
#define K1    4608        // 8*512 spline + 512 silu (= 576 groups, no pad)
#define G1    64          // silu groups layer 1
#define I2    2049
#define O2    512
#define K2    18560       // 8*2049 spline + 2049 silu + 119 pad = 2320 groups
#define G2    271         // silu(+pad) groups layer 2
#define SPLITS2 8
#define KLEN2 2368        // 37*64; last slice clamps to 31 iters
#define NBY   32          // T_TOK/128, both layers

typedef __attribute__((ext_vector_type(8))) short short8;
typedef __attribute__((ext_vector_type(4))) float floatx4;
typedef __attribute__((address_space(3))) void* lds_ptr_t;
typedef const __attribute__((address_space(1))) void* gmem_ptr_t;

__device__ __forceinline__ unsigned short f2bf(float f) {   // RNE (prep kernels)
  union { __hip_bfloat16 h; unsigned short u; } cv;
  cv.h = __float2bfloat16(f);
  return cv.u;
}
__device__ __forceinline__ unsigned bfr(float f) {          // cheap near-RNE (hot path)
  union { float f; unsigned u; } c; c.f = f;
  return (c.u + 0x8000u) >> 16;
}
__device__ __forceinline__ float silu_f(float x) { return x / (1.0f + __expf(-x)); }

// All 8 cubic-basis slots for one group as 8 bf16 in a uint4 (branchless funnel shift).
__device__ __forceinline__ uint4 spline_pack(float h) {
  float u = (h + 2.2f) * 2.5f;
  int ji = (int)u;
  ji = ji < 0 ? 0 : (ji > 10 ? 10 : ji);
  float t = u - (float)ji;
  float it = 1.0f - t, t2 = t * t, t3 = t2 * t;
  float b0 = it * it * it * (1.0f / 6.0f);
  float b1 = (3.0f * t3 - 6.0f * t2 + 4.0f) * (1.0f / 6.0f);
  float b2 = (-3.0f * t3 + 3.0f * t2 + 3.0f * t + 1.0f) * (1.0f / 6.0f);
  float b3 = t3 * (1.0f / 6.0f);
  unsigned pk01 = bfr(b0) | (bfr(b1) << 16);
  unsigned pk23 = bfr(b2) | (bfr(b3) << 16);
  unsigned long long p64 = (unsigned long long)pk01 | ((unsigned long long)pk23 << 32);
  bool inR = (h >= -2.2f) && (h < 2.2f);
  p64 = inR ? p64 : 0ull;
  int sh = (ji - 3) * 16;
  int shr = sh < 0 ? -sh : 0;
  int shl = sh < 0 ? 0 : sh;
  __uint128_t v = ((__uint128_t)(p64 >> shr)) << shl;
  union { __uint128_t q; uint4 u4; } cv;
  cv.q = v;
  return cv.u4;
}

// 32x32 LDS-tiled transpose: src (R x C) -> dst (C x R). R,C multiples of 32.
__global__ void transpose_kernel(const float* __restrict__ src, float* __restrict__ dst,
                                 int R, int C) {
  __shared__ float t[32][33];
  int c0 = blockIdx.x * 32, r0 = blockIdx.y * 32;
  int tx = threadIdx.x & 31, ty = threadIdx.x >> 5;   // 32 x 8
#pragma unroll
  for (int i = 0; i < 32; i += 8)
    t[ty + i][tx] = src[(size_t)(r0 + ty + i) * C + c0 + tx];
  __syncthreads();
#pragma unroll
  for (int i = 0; i < 32; i += 8)
    dst[(size_t)(c0 + ty + i) * R + r0 + tx] = t[tx][ty + i];
}

// SPK[g][m] = uint4 of 8 bf16: silu(St[g*8+c, m]) for c=0..7, 0 beyond I. St is (I x M).
__global__ void silu_pack_kernel(const float* __restrict__ St, uint4* __restrict__ SPK,
                                 int I, int M) {
  int m = blockIdx.x * 256 + threadIdx.x;
  int g = blockIdx.y;
  int off0 = g * 8;
  union { unsigned short s[8]; uint4 v; } pk;
#pragma unroll
  for (int c = 0; c < 8; ++c) {
    int off = off0 + c;
    float v = 0.0f;
    if (off < I) v = silu_f(St[(size_t)off * M + m]);
    pk.s[c] = f2bf(v);
  }
  SPK[(size_t)g * M + m] = pk.v;
}

// W1'[o,k]: k<4096 -> spline_w1[o,k>>3,k&7]*scaler1[o,k>>3]; else base_w1; o>=2049 -> 0
__global__ void pack_w1_kernel(const float* __restrict__ bw, const float* __restrict__ sw,
                               const float* __restrict__ sc, unsigned short* __restrict__ W) {
  int k = blockIdx.x * 256 + threadIdx.x;  // grid exact: 18*256 = 4608
  int o = blockIdx.y;                      // < 2176
  float v = 0.0f;
  if (o < O1) {
    if (k < 4096) v = sw[(size_t)o * 4096 + k] * sc[(size_t)o * I1 + (k >> 3)];
    else          v = bw[(size_t)o * I1 + (k - 4096)];
  }
  W[(size_t)o * K1 + k] = f2bf(v);
}

// W2'[o,k]: k<16392 -> spline_w2*scaler2; k<18441 -> base_w2; else 0
__global__ void pack_w2_kernel(const float* __restrict__ bw, const float* __restrict__ sw,
                               const float* __restrict__ sc, unsigned short* __restrict__ W) {
  int k = blockIdx.x * 256 + threadIdx.x;
  if (k >= K2) return;
  int o = blockIdx.y;                      // < 512
  float v = 0.0f;
  if (k < 16392)      v = sw[(size_t)o * 16392 + k] * sc[(size_t)o * I2 + (k >> 3)];
  else if (k < 18441) v = bw[(size_t)o * I2 + (k - 16392)];
  W[(size_t)o * K2 + k] = f2bf(v);
}

// Fused KAN-expand + GEMM.
//   St  : (I x M) fp32 transposed pre-activations (spline source; lane=m coalesced)
//   SPK : (G x M) uint4 pre-packed silu bf16x8 groups (G = Ktot/8 - I, pad baked in)
//   Bw  : (Nrows x Ktot) bf16, staged via global_load_lds w16 + XOR chunk swizzle
//   A[m,k] generated per K-tile into swizzled LDS; sources prefetched 1 iter ahead.
// 1-D grid, XCD-swizzled decode: all bx-siblings (same source window) share Lb%8.
// storeMode 1: C[n*ldc + m] float4 (transposed store). 2: atomicAdd C[m*ldc+n].
__global__ __launch_bounds__(256, 4)
void kan_gemm_kernel(const float* __restrict__ St, const uint4* __restrict__ SPK,
                     const unsigned short* __restrict__ Bw, float* __restrict__ C,
                     int I, int Ktot, int M, int N, int ldc, int kLen,
                     int nBx, int storeMode)
{
  __shared__ __align__(16) unsigned short As[128 * 64];
  __shared__ __align__(16) unsigned short Bs[128 * 64];

  // Grid decode: Lb = (p&7) + 8*(bx + nBx*(p>>3)), p = by + NBY*bz
  const int Lb = blockIdx.x;
  const int m8 = Lb & 7;
  const int r  = Lb >> 3;
  const int bx = r % nBx;
  const int p  = m8 + ((r / nBx) << 3);
  const int by = p & (NBY - 1);
  const int bz = p >> 5;                   // NBY = 32

  const int tid = threadIdx.x;
  const int ks = bz * kLen;
  int ke = ks + kLen; if (ke > Ktot) ke = Ktot;

  const int w = tid >> 6, L = tid & 63, q = L >> 4, ln = L & 15;
  const int wm = (w & 1) << 6, wn = (w >> 1) << 6;

  // Generator mapping: thread -> (m-row = tid&127, 4 groups starting at gh*4)
  const int row = tid & 127;
  const int gh  = tid >> 7;                // wave-uniform
  const int mGlob = by * 128 + row;
  const float* s0  = St + mGlob;           // + gi*M -> feature gi, lane=m coalesced
  const uint4* sp0 = SPK + mGlob;          // + g*M

  floatx4 zf = {0.f, 0.f, 0.f, 0.f};
  floatx4 acc[4][4];
#pragma unroll
  for (int mt = 0; mt < 4; ++mt)
#pragma unroll
    for (int nt = 0; nt < 4; ++nt)
      acc[mt][nt] = zf;

  // B staging: 4 chunks/thread, lane-contiguous LDS dest (wave-uniform base + lane*16)
  const unsigned short* gb[4];
  int ldsOff[4];
#pragma unroll
  for (int r4 = 0; r4 < 4; ++r4) {
    int e = r4 * 256 + tid;
    int br = e >> 3;
    int cg = (e & 7) ^ (br & 7);
    gb[r4] = Bw + ((long)bx * 128 + br) * (long)Ktot + ks + cg * 8;
    ldsOff[r4] = e * 8;
  }

  // --- source prefetch: cur = iter kc, nxt = iter kc+64 ---
  uint4 cur[4], nxt[4];
#pragma unroll
  for (int j2 = 0; j2 < 4; ++j2) {         // prologue load (iter 0)
    int gi = (ks >> 3) + gh * 4 + j2;
    if (gi < I) cur[j2].x = __float_as_uint(s0[(size_t)gi * M]);
    else        cur[j2]   = sp0[(size_t)(gi - I) * M];
  }

  for (int kc = ks; kc < ke; kc += 64) {
    __syncthreads();                        // prior MFMA done reading LDS
#pragma unroll
    for (int r4 = 0; r4 < 4; ++r4) {        // B DMA: in flight during generation
      __builtin_amdgcn_global_load_lds((gmem_ptr_t)gb[r4], (lds_ptr_t)&Bs[ldsOff[r4]], 16, 0, 0);
      gb[r4] += 64;
    }
    if (kc + 64 < ke) {                     // issue next iter's source loads NOW
#pragma unroll
      for (int j2 = 0; j2 < 4; ++j2) {
        int gi = ((kc + 64) >> 3) + gh * 4 + j2;
        if (gi < I) nxt[j2].x = __float_as_uint(s0[(size_t)gi * M]);
        else        nxt[j2]   = sp0[(size_t)(gi - I) * M];
      }
    }

    const int gBase = (kc >> 3) + gh * 4;
#pragma unroll
    for (int j2 = 0; j2 < 4; ++j2) {        // generate A tile from cur (no global waits)
      int g  = gh * 4 + j2;                 // local group 0..7 (wave-uniform)
      int gi = gBase + j2;
      int pos = row * 64 + ((g ^ (row & 7)) << 3);
      uint4 val;
      if (gi < I) val = spline_pack(__uint_as_float(cur[j2].x));
      else        val = cur[j2];            // pre-packed silu / pad
      *(uint4*)&As[pos] = val;              // one ds_write_b128, swizzle-spread
    }
    __syncthreads();                        // A generated + B DMA (+ nxt loads) drained

#pragma unroll
    for (int s = 0; s < 2; ++s) {
      short8 af[4], bf[4];
#pragma unroll
      for (int mt = 0; mt < 4; ++mt) {
        int rr = wm + mt * 16 + ln;
        int cl = ((s << 2) | q) ^ (rr & 7);
        af[mt] = *(const short8*)&As[rr * 64 + cl * 8];
      }
#pragma unroll
      for (int nt = 0; nt < 4; ++nt) {
        int rr = wn + nt * 16 + ln;
        int cl = ((s << 2) | q) ^ (rr & 7);
        bf[nt] = *(const short8*)&Bs[rr * 64 + cl * 8];
      }
#pragma unroll
      for (int mt = 0; mt < 4; ++mt)
#pragma unroll
        for (int nt = 0; nt < 4; ++nt)
          acc[mt][nt] = __builtin_amdgcn_mfma_f32_16x16x32_bf16(af[mt], bf[nt], acc[mt][nt], 0, 0, 0);
    }
#pragma unroll
    for (int j2 = 0; j2 < 4; ++j2) cur[j2] = nxt[j2];
  }

  // Epilogue. D layout: col = lane&15 (n), row = q*4+reg (m)  [m89-verified]
  if (storeMode == 1) {                     // transposed float4 store (layer 1 -> H^T)
#pragma unroll
    for (int mt = 0; mt < 4; ++mt) {
#pragma unroll
      for (int nt = 0; nt < 4; ++nt) {
        int n = bx * 128 + wn + nt * 16 + ln;
        if (n < N) {
          int m0 = by * 128 + wm + mt * 16 + q * 4;
          *(float4*)&C[(size_t)n * ldc + m0] = *(float4*)&acc[mt][nt];
        }
      }
    }
  } else {                                  // atomic accumulate (layer 2, split-K)
#pragma unroll
    for (int mt = 0; mt < 4; ++mt) {
#pragma unroll
      for (int nt = 0; nt < 4; ++nt) {
        int n = bx * 128 + wn + nt * 16 + ln;
        if (n < N) {
          int m0 = by * 128 + wm + mt * 16 + q * 4;
#pragma unroll
          for (int rg = 0; rg < 4; ++rg)
            atomicAdd(&C[(size_t)(m0 + rg) * ldc + n], acc[mt][nt][rg]);
        }
      }
    }
  }
}

extern "C" void kernel_launch(void* const* d_in, const int* in_sizes, int n_in,
                              void* d_out, int out_size, void* d_ws, size_t ws_size,
                              hipStream_t stream) {
  const float* x   = (const float*)d_in[0];
  const float* bw1 = (const float*)d_in[1];
  const float* sw1 = (const float*)d_in[2];
  const float* sc1 = (const float*)d_in[3];
  const float* bw2 = (const float*)d_in[4];
  const float* sw2 = (const float*)d_in[5];
  const float* sc2 = (const float*)d_in[6];
  float* out = (float*)d_out;

  // Workspace: Xt | H0t | W1' | W2' | SPK1 | SPK2  (~103 MB total)
  float* Xt  = (float*)d_ws;                                   //  8.39 MB
  float* H0t = Xt + (size_t)I1 * T_TOK;                        // 33.57 MB
  unsigned short* W1 = (unsigned short*)(H0t + (size_t)O1 * T_TOK);  // 20.05 MB
  unsigned short* W2 = W1 + (size_t)O1P * K1;                        // 19.01 MB
  uint4* SPK1 = (uint4*)(W2 + (size_t)O2 * K2);                //  4.19 MB
  uint4* SPK2 = SPK1 + (size_t)G1 * T_TOK;                     // 17.76 MB

  hipMemsetAsync(d_out, 0, (size_t)out_size * sizeof(float), stream);

  transpose_kernel<<<dim3(I1 / 32, T_TOK / 32), 256, 0, stream>>>(x, Xt, T_TOK, I1);
  pack_w1_kernel<<<dim3(K1 / 256, O1P), 256, 0, stream>>>(bw1, sw1, sc1, W1);
  pack_w2_kernel<<<dim3((K2 + 255) / 256, O2), 256, 0, stream>>>(bw2, sw2, sc2, W2);
  silu_pack_kernel<<<dim3(T_TOK / 256, G1), 256, 0, stream>>>(Xt, SPK1, I1, T_TOK);

  // Layer 1: H^T = expand(x) @ W1'^T. M=4096, N=2049(rows pad 2176), K=4608.
  // 17*32 = 544 blocks, single-K (no split), transposed float4 store.
  kan_gemm_kernel<<<O1P / 128 * NBY, 256, 0, stream>>>(
      Xt, SPK1, W1, H0t, I1, K1, T_TOK, O1, T_TOK, K1, O1P / 128, 1);

  silu_pack_kernel<<<dim3(T_TOK / 256, G2), 256, 0, stream>>>(H0t, SPK2, I2, T_TOK);

  // Layer 2: out += expand(H) @ W2'^T. M=4096, N=512, K=18560, split-K=8 -> 1024 blocks.
  kan_gemm_kernel<<<O2 / 128 * NBY * SPLITS2, 256, 0, stream>>>(
      H0t, SPK2, W2, out, I2, K2, T_TOK, O2, O2, KLEN2, O2 / 128, 2);
}